// Round 2
// baseline (3351.751 us; speedup 1.0000x reference)
//
#include <hip/hip_runtime.h>
#include <hip/hip_bf16.h>
#include <stdint.h>
#include <stddef.h>

// Problem constants (fixed by the reference)
#define B_ 4
#define N_ 2048
#define E_ 1024
#define H_ 16
#define D_ 64
// SCALE = 1/sqrt(64) = 0.125 exactly
//
// DTYPE NOTE (round-1 post-mortem): reference declares ALL tensors float32.
// Round-0 kernel read inputs as bf16 -> reinterpreted fp32 bit patterns ->
// NaN (low mantissa bits as bf16 hit exponent 0xFF ~0.4%/elem). Inputs are
// const float*, output is float*. Internally we convert to bf16 for MFMA
// (error ~1e-2 << 8.19e-2 threshold).

using bf16 = __hip_bfloat16;
typedef __bf16 bf16x8 __attribute__((ext_vector_type(8)));   // 4 VGPRs, MFMA A/B frag
typedef float  f32x4  __attribute__((ext_vector_type(4)));   // MFMA C/D frag

// ---- dtype helpers --------------------------------------------------------
__device__ inline bf16x8 load8(const float* p) {
    f32x4 a = *(const f32x4*)p;
    f32x4 b = *(const f32x4*)(p + 4);
    bf16x8 r;
#pragma unroll
    for (int e = 0; e < 4; e++) { r[e] = (__bf16)a[e]; r[e + 4] = (__bf16)b[e]; }
    return r;
}
__device__ inline bf16x8 load8(const bf16* p) { return *(const bf16x8*)p; }

__device__ inline void store_elem(float* C, size_t idx, float v) { C[idx] = v; }
__device__ inline void store_elem(bf16* C, size_t idx, float v) {
    C[idx] = __float2bfloat16(v);
}

// ---------------------------------------------------------------------------
// GEMM: C[M,Nc] = A[M,K] @ W[Nc,K]^T  (+ optional fp32 bias), fp32 accumulate
// via v_mfma_f32_16x16x32_bf16. A and W row-major, K contiguous.
// Tile: 128x128 per block (256 threads = 4 waves in 2x2), BK=32.
// Fragment layouts (verified, learn_hip m89/m91):
//   A: lane holds A[m=lane&15][k=(lane>>4)*8 + j], j=0..7
//   B: lane holds B[k=(lane>>4)*8 + j][n=lane&15] == W[n][k]
//   C/D: col = lane&15, row = (lane>>4)*4 + reg
// ---------------------------------------------------------------------------
template <typename TA, typename TW, typename TC>
__global__ __launch_bounds__(256) void gemm_bt(
    const TA* __restrict__ A, const TW* __restrict__ W,
    TC* __restrict__ C, const float* __restrict__ bias,
    int M, int Ncols, int K)
{
    __shared__ bf16 As[128 * 32];   // 8 KB
    __shared__ bf16 Bs[128 * 32];   // 8 KB

    const int tid  = threadIdx.x;
    const int lane = tid & 63;
    const int wave = tid >> 6;
    const int wr   = wave >> 1;     // wave row (0..1)
    const int wc   = wave & 1;      // wave col (0..1)
    const int r    = lane & 15;
    const int quad = lane >> 4;

    const int m0 = blockIdx.y * 128;
    const int n0 = blockIdx.x * 128;

    f32x4 acc[4][4];
#pragma unroll
    for (int i = 0; i < 4; i++)
#pragma unroll
        for (int j = 0; j < 4; j++)
            acc[i][j] = {0.0f, 0.0f, 0.0f, 0.0f};

    for (int k0 = 0; k0 < K; k0 += 32) {
        __syncthreads();
        // Stage A-tile and W-tile: 128 rows x 32 elems each.
        // 512 8-elem chunks per tile / 256 threads = 2 chunks each.
#pragma unroll
        for (int s = 0; s < 2; s++) {
            int idx = tid + s * 256;
            int row = idx >> 2;          // 4 chunks per 32-element row
            int cc  = (idx & 3) * 8;
            *(bf16x8*)&As[row * 32 + cc] =
                load8(&A[(size_t)(m0 + row) * K + k0 + cc]);
            *(bf16x8*)&Bs[row * 32 + cc] =
                load8(&W[(size_t)(n0 + row) * K + k0 + cc]);
        }
        __syncthreads();

        bf16x8 a[4], b[4];
#pragma unroll
        for (int mt = 0; mt < 4; mt++)
            a[mt] = *(const bf16x8*)&As[(wr * 64 + mt * 16 + r) * 32 + quad * 8];
#pragma unroll
        for (int nt = 0; nt < 4; nt++)
            b[nt] = *(const bf16x8*)&Bs[(wc * 64 + nt * 16 + r) * 32 + quad * 8];
#pragma unroll
        for (int mt = 0; mt < 4; mt++)
#pragma unroll
            for (int nt = 0; nt < 4; nt++)
                acc[mt][nt] = __builtin_amdgcn_mfma_f32_16x16x32_bf16(
                    a[mt], b[nt], acc[mt][nt], 0, 0, 0);
    }

    // Epilogue: C/D layout col=lane&15, row=quad*4+reg
#pragma unroll
    for (int mt = 0; mt < 4; mt++) {
#pragma unroll
        for (int nt = 0; nt < 4; nt++) {
            const int col = n0 + wc * 64 + nt * 16 + r;
            float bv = bias ? bias[col] : 0.0f;
#pragma unroll
            for (int rg = 0; rg < 4; rg++) {
                const int row = m0 + wr * 64 + mt * 16 + quad * 4 + rg;
                store_elem(C, (size_t)row * Ncols + col, acc[mt][nt][rg] + bv);
            }
        }
    }
}

// ---------------------------------------------------------------------------
// Flash-style causal attention over projected q/k/v stored as [B, N, H*D] bf16.
// One block = 64 query rows of one (b,h). 256 threads.
//   thread -> (qi = tid>>2, g = tid&3) computes S[qi][g*16..+16] and
//   accumulates O[qi][g*16..+16]. Row reductions via quad shuffles.
// K/V tiles pre-converted to fp32 in LDS so hot loops are fma+ds_read_b128.
// ---------------------------------------------------------------------------
__global__ __launch_bounds__(256) void attn_fwd(
    const bf16* __restrict__ q, const bf16* __restrict__ k,
    const bf16* __restrict__ v, bf16* __restrict__ o)
{
    __shared__ bf16  Qs [64 * 64];   // 8 KB
    __shared__ float Ksf[64 * 68];   // 17 KB (padded: row stride 68)
    __shared__ float Vsf[64 * 68];   // 17 KB
    __shared__ float Ps [64 * 65];   // 16.6 KB (padded: stride 65)

    const int tid = threadIdx.x;
    const int qi  = tid >> 2;        // 0..63
    const int g   = tid & 3;         // 0..3
    const int bh  = blockIdx.y;
    const int b   = bh >> 4;
    const int h   = bh & 15;
    const int q0  = blockIdx.x * 64;

    const size_t baseq = ((size_t)b * N_ + q0) * E_ + (size_t)h * D_;
    const size_t basek = ((size_t)b * N_) * E_ + (size_t)h * D_;

    // Load Q tile (64 rows x 64 bf16 = 512 8-elem chunks / 256 threads)
#pragma unroll
    for (int s = 0; s < 2; s++) {
        int idx = tid + s * 256;
        int row = idx >> 3;
        int c   = (idx & 7) * 8;
        *(uint4*)&Qs[row * 64 + c] =
            *(const uint4*)&q[baseq + (size_t)row * E_ + c];
    }

    float m_old = -1e30f, l_old = 0.0f;
    float o_acc[16];
#pragma unroll
    for (int e = 0; e < 16; e++) o_acc[e] = 0.0f;

    const int ntiles = blockIdx.x + 1;      // causal: keys 0 .. q0+63
    const int qg = q0 + qi;

    for (int t = 0; t < ntiles; t++) {
        const int j0 = t * 64;
        __syncthreads();   // previous tile's PV done before restaging K/V
#pragma unroll
        for (int s = 0; s < 2; s++) {
            int idx = tid + s * 256;
            int row = idx >> 3;
            int c   = (idx & 7) * 8;
            bf16x8 kv = *(const bf16x8*)&k[basek + (size_t)(j0 + row) * E_ + c];
            bf16x8 vv = *(const bf16x8*)&v[basek + (size_t)(j0 + row) * E_ + c];
#pragma unroll
            for (int e = 0; e < 8; e++) {
                Ksf[row * 68 + c + e] = (float)kv[e];
                Vsf[row * 68 + c + e] = (float)vv[e];
            }
        }
        __syncthreads();

        // S[qi][g*16+kk] = q[qi] . k[j]
        float s_val[16];
#pragma unroll
        for (int kk = 0; kk < 16; kk++) s_val[kk] = 0.0f;
#pragma unroll
        for (int dc = 0; dc < 8; dc++) {
            bf16x8 qv = *(const bf16x8*)&Qs[qi * 64 + dc * 8];
            float qf[8];
#pragma unroll
            for (int e = 0; e < 8; e++) qf[e] = (float)qv[e];
#pragma unroll
            for (int kk = 0; kk < 16; kk++) {
                const int kj = g * 16 + kk;
                f32x4 ka = *(const f32x4*)&Ksf[kj * 68 + dc * 8];
                f32x4 kb = *(const f32x4*)&Ksf[kj * 68 + dc * 8 + 4];
                s_val[kk] += qf[0] * ka[0] + qf[1] * ka[1] + qf[2] * ka[2] +
                             qf[3] * ka[3] + qf[4] * kb[0] + qf[5] * kb[1] +
                             qf[6] * kb[2] + qf[7] * kb[3];
            }
        }

        // causal mask + scale
#pragma unroll
        for (int kk = 0; kk < 16; kk++) {
            const int kgl = j0 + g * 16 + kk;
            s_val[kk] = (kgl <= qg) ? s_val[kk] * 0.125f : -1e30f;
        }

        // online softmax: row max over 64 entries (16 local + quad shuffle)
        float mx = s_val[0];
#pragma unroll
        for (int kk = 1; kk < 16; kk++) mx = fmaxf(mx, s_val[kk]);
        mx = fmaxf(mx, __shfl_xor(mx, 1));
        mx = fmaxf(mx, __shfl_xor(mx, 2));
        const float m_new = fmaxf(m_old, mx);
        const float alpha = __expf(m_old - m_new);

        float lsum = 0.0f;
#pragma unroll
        for (int kk = 0; kk < 16; kk++) {
            float p = __expf(s_val[kk] - m_new);
            Ps[qi * 65 + g * 16 + kk] = p;
            lsum += p;
        }
        lsum += __shfl_xor(lsum, 1);
        lsum += __shfl_xor(lsum, 2);
        l_old = l_old * alpha + lsum;
        m_old = m_new;
        __syncthreads();   // Ps visible to all readers

        // O[qi][g*16+e] = O*alpha + sum_j P[qi][j] * V[j][g*16+e]
#pragma unroll
        for (int e = 0; e < 16; e++) o_acc[e] *= alpha;
        for (int j = 0; j < 64; j++) {
            const float p = Ps[qi * 65 + j];
            const float* vr = &Vsf[j * 68 + g * 16];
            f32x4 v0 = *(const f32x4*)&vr[0];
            f32x4 v1 = *(const f32x4*)&vr[4];
            f32x4 v2 = *(const f32x4*)&vr[8];
            f32x4 v3 = *(const f32x4*)&vr[12];
#pragma unroll
            for (int e = 0; e < 4; e++) {
                o_acc[e]      += p * v0[e];
                o_acc[e + 4]  += p * v1[e];
                o_acc[e + 8]  += p * v2[e];
                o_acc[e + 12] += p * v3[e];
            }
        }
    }

    // normalize + store 16 bf16 (32 B contiguous per thread)
    const float inv_l = 1.0f / l_old;
    bf16x8 w0, w1;
#pragma unroll
    for (int e = 0; e < 8; e++) {
        w0[e] = (__bf16)(o_acc[e] * inv_l);
        w1[e] = (__bf16)(o_acc[e + 8] * inv_l);
    }
    const size_t baseo = ((size_t)b * N_ + q0 + qi) * E_ + (size_t)h * D_ + g * 16;
    *(bf16x8*)&o[baseo]     = w0;
    *(bf16x8*)&o[baseo + 8] = w1;
}

// ---------------------------------------------------------------------------
// Inputs (setup_inputs order): xq, xk, xv, attn_mask, Wq, Wk, Wv, Wo, bo
// All float32. attn_mask is the causal triu mask — applied structurally.
// ws layout: q | k | v | attn_out, each B*N*E bf16 (16.8 MB each, 67 MB total)
// ---------------------------------------------------------------------------
extern "C" void kernel_launch(void* const* d_in, const int* in_sizes, int n_in,
                              void* d_out, int out_size, void* d_ws, size_t ws_size,
                              hipStream_t stream) {
    const float* xq = (const float*)d_in[0];
    const float* xk = (const float*)d_in[1];
    const float* xv = (const float*)d_in[2];
    const float* Wq = (const float*)d_in[4];
    const float* Wk = (const float*)d_in[5];
    const float* Wv = (const float*)d_in[6];
    const float* Wo = (const float*)d_in[7];
    const float* bo = (const float*)d_in[8];
    float* out = (float*)d_out;

    const size_t elems = (size_t)B_ * N_ * E_;   // 8388608
    bf16* q  = (bf16*)d_ws;
    bf16* kk = q + elems;
    bf16* vv = kk + elems;
    bf16* ao = vv + elems;

    dim3 blk(256);
    dim3 gproj(E_ / 128, (B_ * N_) / 128);       // 8 x 64 = 512 blocks
    gemm_bt<float, float, bf16><<<gproj, blk, 0, stream>>>(
        xq, Wq, q,  nullptr, B_ * N_, E_, E_);
    gemm_bt<float, float, bf16><<<gproj, blk, 0, stream>>>(
        xk, Wk, kk, nullptr, B_ * N_, E_, E_);
    gemm_bt<float, float, bf16><<<gproj, blk, 0, stream>>>(
        xv, Wv, vv, nullptr, B_ * N_, E_, E_);

    dim3 gattn(N_ / 64, B_ * H_);                // 32 x 64 = 2048 blocks
    attn_fwd<<<gattn, blk, 0, stream>>>(q, kk, vv, ao);

    gemm_bt<bf16, float, float><<<gproj, blk, 0, stream>>>(
        ao, Wo, out, bo, B_ * N_, E_, E_);
}

// Round 3
// 600.190 us; speedup vs baseline: 5.5845x; 5.5845x over previous
//
#include <hip/hip_runtime.h>
#include <hip/hip_bf16.h>
#include <stdint.h>
#include <stddef.h>

// Problem constants (fixed by the reference)
#define B_ 4
#define N_ 2048
#define E_ 1024
#define H_ 16
#define D_ 64
// SCALE = 1/sqrt(64) = 0.125 exactly
//
// DTYPE NOTE: reference tensors are all float32. Inputs const float*, output
// float*. Internally bf16 for MFMA (error ~1.6e-2 << 8.19e-2 threshold).

using bf16 = __hip_bfloat16;
typedef __bf16 bf16x8 __attribute__((ext_vector_type(8)));   // 4 VGPRs, MFMA A/B frag
typedef float  f32x4  __attribute__((ext_vector_type(4)));   // MFMA C/D frag

// ---- dtype helpers --------------------------------------------------------
__device__ inline bf16x8 load8(const float* p) {
    f32x4 a = *(const f32x4*)p;
    f32x4 b = *(const f32x4*)(p + 4);
    bf16x8 r;
#pragma unroll
    for (int e = 0; e < 4; e++) { r[e] = (__bf16)a[e]; r[e + 4] = (__bf16)b[e]; }
    return r;
}
__device__ inline bf16x8 load8(const bf16* p) { return *(const bf16x8*)p; }

__device__ inline void store_elem(float* C, size_t idx, float v) { C[idx] = v; }
__device__ inline void store_elem(bf16* C, size_t idx, float v) {
    C[idx] = __float2bfloat16(v);
}

// ---------------------------------------------------------------------------
// GEMM: C[M,Nc] = A[M,K] @ W[Nc,K]^T (+ optional fp32 bias), fp32 accumulate
// via v_mfma_f32_16x16x32_bf16. 128x128 tile, BK=32, 4 waves.
// (unchanged from round 2 — attention dominates; GEMM levers next round)
// ---------------------------------------------------------------------------
template <typename TA, typename TW, typename TC>
__global__ __launch_bounds__(256) void gemm_bt(
    const TA* __restrict__ A, const TW* __restrict__ W,
    TC* __restrict__ C, const float* __restrict__ bias,
    int M, int Ncols, int K)
{
    __shared__ bf16 As[128 * 32];
    __shared__ bf16 Bs[128 * 32];

    const int tid  = threadIdx.x;
    const int lane = tid & 63;
    const int wave = tid >> 6;
    const int wr   = wave >> 1;
    const int wc   = wave & 1;
    const int r    = lane & 15;
    const int quad = lane >> 4;

    const int m0 = blockIdx.y * 128;
    const int n0 = blockIdx.x * 128;

    f32x4 acc[4][4];
#pragma unroll
    for (int i = 0; i < 4; i++)
#pragma unroll
        for (int j = 0; j < 4; j++)
            acc[i][j] = {0.0f, 0.0f, 0.0f, 0.0f};

    for (int k0 = 0; k0 < K; k0 += 32) {
        __syncthreads();
#pragma unroll
        for (int s = 0; s < 2; s++) {
            int idx = tid + s * 256;
            int row = idx >> 2;
            int cc  = (idx & 3) * 8;
            *(bf16x8*)&As[row * 32 + cc] =
                load8(&A[(size_t)(m0 + row) * K + k0 + cc]);
            *(bf16x8*)&Bs[row * 32 + cc] =
                load8(&W[(size_t)(n0 + row) * K + k0 + cc]);
        }
        __syncthreads();

        bf16x8 a[4], b[4];
#pragma unroll
        for (int mt = 0; mt < 4; mt++)
            a[mt] = *(const bf16x8*)&As[(wr * 64 + mt * 16 + r) * 32 + quad * 8];
#pragma unroll
        for (int nt = 0; nt < 4; nt++)
            b[nt] = *(const bf16x8*)&Bs[(wc * 64 + nt * 16 + r) * 32 + quad * 8];
#pragma unroll
        for (int mt = 0; mt < 4; mt++)
#pragma unroll
            for (int nt = 0; nt < 4; nt++)
                acc[mt][nt] = __builtin_amdgcn_mfma_f32_16x16x32_bf16(
                    a[mt], b[nt], acc[mt][nt], 0, 0, 0);
    }

#pragma unroll
    for (int mt = 0; mt < 4; mt++) {
#pragma unroll
        for (int nt = 0; nt < 4; nt++) {
            const int col = n0 + wc * 64 + nt * 16 + r;
            float bv = bias ? bias[col] : 0.0f;
#pragma unroll
            for (int rg = 0; rg < 4; rg++) {
                const int row = m0 + wr * 64 + mt * 16 + quad * 4 + rg;
                store_elem(C, (size_t)row * Ncols + col, acc[mt][nt][rg] + bv);
            }
        }
    }
}

// ---------------------------------------------------------------------------
// MFMA flash attention (round-2 rewrite; old version was latency/bank-conflict
// bound: VALUBusy 14.7%, MfmaUtil 0, 4.3e8 conflict cycles).
//
// Block = 64 q-rows of one (b,h); 4 waves; wave w owns q-rows [w*16, w*16+16).
// Per 64-key tile:
//   QK^T: A = Q (regs, loaded once), B = Ks (row-major [key][d], b128 frags)
//   softmax: in-wave (C-layout row = quad*4+reg; reduce via shfl_xor 1,2,4,8)
//   P: bf16 -> Ps LDS (rows are wave-private; no barrier needed)
//   PV : A = Ps (b128), B = Vt (V transposed [d][key] in LDS, b128)
// All LDS row strides = 72 elems (36 dwords, ≡4 mod 32) -> worst 2-way
// aliasing = free (m136). LDS total 27.6 KB -> ~5 blocks/CU.
// ---------------------------------------------------------------------------
__global__ __launch_bounds__(256) void attn_fwd(
    const bf16* __restrict__ q, const bf16* __restrict__ k,
    const bf16* __restrict__ v, bf16* __restrict__ o)
{
    constexpr int LS = 72;
    __shared__ bf16 Ks[64 * LS];   // [key][d]
    __shared__ bf16 Vt[64 * LS];   // [d][key]  (transposed)
    __shared__ bf16 Ps[64 * LS];   // [q][key]  (wave-private row strips)

    const int tid  = threadIdx.x;
    const int lane = tid & 63;
    const int wave = tid >> 6;
    const int r    = lane & 15;
    const int quad = lane >> 4;

    const int bh = blockIdx.y;
    const int b  = bh >> 4;
    const int h  = bh & 15;
    const int q0 = blockIdx.x * 64;

    const size_t basek = (size_t)b * N_ * E_ + (size_t)h * D_;

    // Q fragments, held in registers for the whole kernel.
    // A-frag: lane holds Q[q = wave*16 + r][d = ks*32 + quad*8 + j]
    bf16x8 qf[2];
    {
        const size_t qrow = ((size_t)b * N_ + q0 + wave * 16 + r) * E_ + h * D_;
        qf[0] = *(const bf16x8*)&q[qrow + quad * 8];
        qf[1] = *(const bf16x8*)&q[qrow + quad * 8 + 32];
    }

    float m_i[4], l_i[4];
    f32x4 o_acc[4];                 // nt = d-group; row = quad*4+reg
#pragma unroll
    for (int rg = 0; rg < 4; rg++) {
        m_i[rg] = -1e30f; l_i[rg] = 0.0f;
        o_acc[rg] = {0.0f, 0.0f, 0.0f, 0.0f};
    }

    const int ntiles = blockIdx.x + 1;     // causal: key tiles 0..blockIdx.x

    for (int t = 0; t < ntiles; t++) {
        const int j0 = t * 64;
        __syncthreads();                   // prev tile's reads of Ks/Vt done

        // ---- stage K row-major: 512 8-elem chunks / 256 threads ----
#pragma unroll
        for (int s = 0; s < 2; s++) {
            int idx = tid + s * 256;
            int key = idx >> 3;
            int c   = (idx & 7) * 8;
            *(bf16x8*)&Ks[key * LS + c] =
                *(const bf16x8*)&k[basek + (size_t)(j0 + key) * E_ + c];
        }
        // ---- stage V transposed: thread -> key-pair kp, d-chunk c ----
        // write ushort2 {V[2kp][d], V[2kp+1][d]} -> Vt[d][2kp] (dword, conflict-free)
        {
            const int kp = tid & 31;
            const int c  = (tid >> 5) * 8;
            bf16x8 v0 = *(const bf16x8*)&v[basek + (size_t)(j0 + 2 * kp) * E_ + c];
            bf16x8 v1 = *(const bf16x8*)&v[basek + (size_t)(j0 + 2 * kp + 1) * E_ + c];
#pragma unroll
            for (int e = 0; e < 8; e++) {
                union { __bf16 hh[2]; uint32_t u; } pk;
                pk.hh[0] = v0[e]; pk.hh[1] = v1[e];
                *(uint32_t*)&Vt[(c + e) * LS + 2 * kp] = pk.u;
            }
        }
        __syncthreads();

        // ---- S = scale * Q K^T  (strip: 16 q-rows x 64 keys per wave) ----
        f32x4 s_frag[4];
#pragma unroll
        for (int nt = 0; nt < 4; nt++) s_frag[nt] = {0.0f, 0.0f, 0.0f, 0.0f};
#pragma unroll
        for (int ks = 0; ks < 2; ks++)
#pragma unroll
            for (int nt = 0; nt < 4; nt++) {
                bf16x8 bfr = *(const bf16x8*)&Ks[(nt * 16 + r) * LS + ks * 32 + quad * 8];
                s_frag[nt] = __builtin_amdgcn_mfma_f32_16x16x32_bf16(
                    qf[ks], bfr, s_frag[nt], 0, 0, 0);
            }

        // scale + causal mask (only the diagonal tile has masked entries)
        if (t == ntiles - 1) {
#pragma unroll
            for (int nt = 0; nt < 4; nt++) {
                const int kgl = j0 + nt * 16 + r;
#pragma unroll
                for (int rg = 0; rg < 4; rg++) {
                    const int qgl = q0 + wave * 16 + quad * 4 + rg;
                    s_frag[nt][rg] = (kgl <= qgl) ? s_frag[nt][rg] * 0.125f : -1e30f;
                }
            }
        } else {
#pragma unroll
            for (int nt = 0; nt < 4; nt++)
#pragma unroll
                for (int rg = 0; rg < 4; rg++)
                    s_frag[nt][rg] *= 0.125f;
        }

        // ---- online softmax, in-wave ----
        float mx[4];
#pragma unroll
        for (int rg = 0; rg < 4; rg++) {
            float m = fmaxf(fmaxf(s_frag[0][rg], s_frag[1][rg]),
                            fmaxf(s_frag[2][rg], s_frag[3][rg]));
            m = fmaxf(m, __shfl_xor(m, 1));
            m = fmaxf(m, __shfl_xor(m, 2));
            m = fmaxf(m, __shfl_xor(m, 4));
            m = fmaxf(m, __shfl_xor(m, 8));
            mx[rg] = m;
        }
        float alpha[4], ls[4];
#pragma unroll
        for (int rg = 0; rg < 4; rg++) {
            const float m_new = fmaxf(m_i[rg], mx[rg]);
            alpha[rg] = __expf(m_i[rg] - m_new);
            m_i[rg] = m_new;
            ls[rg] = 0.0f;
        }
        // p = exp(s - m); write to Ps (bf16, wave-private rows)
#pragma unroll
        for (int nt = 0; nt < 4; nt++)
#pragma unroll
            for (int rg = 0; rg < 4; rg++) {
                const float p = __expf(s_frag[nt][rg] - m_i[rg]);
                ls[rg] += p;
                Ps[(wave * 16 + quad * 4 + rg) * LS + nt * 16 + r] = __float2bfloat16(p);
            }
#pragma unroll
        for (int rg = 0; rg < 4; rg++) {
            float s = ls[rg];
            s += __shfl_xor(s, 1);
            s += __shfl_xor(s, 2);
            s += __shfl_xor(s, 4);
            s += __shfl_xor(s, 8);
            l_i[rg] = l_i[rg] * alpha[rg] + s;
        }
        // rescale O by alpha (per row = per reg)
#pragma unroll
        for (int nt = 0; nt < 4; nt++)
#pragma unroll
            for (int rg = 0; rg < 4; rg++)
                o_acc[nt][rg] *= alpha[rg];

        // ---- O += P V  (A = Ps strip, B = Vt) ----
#pragma unroll
        for (int ks = 0; ks < 2; ks++) {
            bf16x8 pa = *(const bf16x8*)&Ps[(wave * 16 + r) * LS + ks * 32 + quad * 8];
#pragma unroll
            for (int nt = 0; nt < 4; nt++) {
                bf16x8 vb = *(const bf16x8*)&Vt[(nt * 16 + r) * LS + ks * 32 + quad * 8];
                o_acc[nt] = __builtin_amdgcn_mfma_f32_16x16x32_bf16(
                    pa, vb, o_acc[nt], 0, 0, 0);
            }
        }
    }

    // ---- normalize + store (C-layout: row = quad*4+reg, col = nt*16+r) ----
    float invl[4];
#pragma unroll
    for (int rg = 0; rg < 4; rg++) invl[rg] = 1.0f / l_i[rg];
    const size_t baseo =
        ((size_t)b * N_ + q0 + wave * 16 + quad * 4) * E_ + (size_t)h * D_;
#pragma unroll
    for (int rg = 0; rg < 4; rg++)
#pragma unroll
        for (int nt = 0; nt < 4; nt++)
            o[baseo + (size_t)rg * E_ + nt * 16 + r] =
                __float2bfloat16(o_acc[nt][rg] * invl[rg]);
}

// ---------------------------------------------------------------------------
// Inputs (setup_inputs order): xq, xk, xv, attn_mask, Wq, Wk, Wv, Wo, bo
// All float32. attn_mask applied structurally (causal).
// ws layout: q | k | v | attn_out, each B*N*E bf16
// ---------------------------------------------------------------------------
extern "C" void kernel_launch(void* const* d_in, const int* in_sizes, int n_in,
                              void* d_out, int out_size, void* d_ws, size_t ws_size,
                              hipStream_t stream) {
    const float* xq = (const float*)d_in[0];
    const float* xk = (const float*)d_in[1];
    const float* xv = (const float*)d_in[2];
    const float* Wq = (const float*)d_in[4];
    const float* Wk = (const float*)d_in[5];
    const float* Wv = (const float*)d_in[6];
    const float* Wo = (const float*)d_in[7];
    const float* bo = (const float*)d_in[8];
    float* out = (float*)d_out;

    const size_t elems = (size_t)B_ * N_ * E_;   // 8388608
    bf16* q  = (bf16*)d_ws;
    bf16* kk = q + elems;
    bf16* vv = kk + elems;
    bf16* ao = vv + elems;

    dim3 blk(256);
    dim3 gproj(E_ / 128, (B_ * N_) / 128);       // 8 x 64 = 512 blocks
    gemm_bt<float, float, bf16><<<gproj, blk, 0, stream>>>(
        xq, Wq, q,  nullptr, B_ * N_, E_, E_);
    gemm_bt<float, float, bf16><<<gproj, blk, 0, stream>>>(
        xk, Wk, kk, nullptr, B_ * N_, E_, E_);
    gemm_bt<float, float, bf16><<<gproj, blk, 0, stream>>>(
        xv, Wv, vv, nullptr, B_ * N_, E_, E_);

    dim3 gattn(N_ / 64, B_ * H_);                // 32 x 64 = 2048 blocks
    attn_fwd<<<gattn, blk, 0, stream>>>(q, kk, vv, ao);

    gemm_bt<bf16, float, float><<<gproj, blk, 0, stream>>>(
        ao, Wo, out, bo, B_ * N_, E_, E_);
}

// Round 4
// 498.975 us; speedup vs baseline: 6.7173x; 1.2028x over previous
//
#include <hip/hip_runtime.h>
#include <hip/hip_bf16.h>
#include <stdint.h>
#include <stddef.h>

// Problem constants (fixed by the reference)
#define B_ 4
#define N_ 2048
#define E_ 1024
#define H_ 16
#define D_ 64
// SCALE = 1/sqrt(64) = 0.125 exactly
// All reference tensors are float32; internally bf16 for MFMA.

using bf16 = __hip_bfloat16;
typedef __bf16 bf16x8 __attribute__((ext_vector_type(8)));   // 4 VGPRs, MFMA A/B frag
typedef float  f32x4  __attribute__((ext_vector_type(4)));   // MFMA C/D frag

// ---- dtype helpers --------------------------------------------------------
__device__ inline bf16x8 load8(const float* p) {
    f32x4 a = *(const f32x4*)p;
    f32x4 b = *(const f32x4*)(p + 4);
    bf16x8 r;
#pragma unroll
    for (int e = 0; e < 4; e++) { r[e] = (__bf16)a[e]; r[e + 4] = (__bf16)b[e]; }
    return r;
}
__device__ inline void store_elem(float* C, size_t idx, float v) { C[idx] = v; }
__device__ inline void store_elem(bf16* C, size_t idx, float v) {
    C[idx] = __float2bfloat16(v);
}

// Async global->LDS, 16 B per lane (LDS dest must be wave-uniform base +
// lane*16 — our As/Bs staging layout is exactly lane-contiguous).
__device__ inline void async_stage16(const bf16* g, bf16* l) {
    __builtin_amdgcn_global_load_lds(
        (const __attribute__((address_space(1))) uint32_t*)g,
        (__attribute__((address_space(3))) uint32_t*)l, 16, 0, 0);
}
// Manual stage for fp32 source: convert to bf16 in VGPRs, ds_write_b128.
__device__ inline void manual_stage16(const float* g, bf16* l) {
    *(bf16x8*)l = load8(g);
}

// ---------------------------------------------------------------------------
// Weight fp32 -> bf16 convert: 4 matrices of E*E, into Wb[4*E*E].
// 512 blocks per weight, 8 elems/thread.
// ---------------------------------------------------------------------------
__global__ __launch_bounds__(256) void cvt_w(
    const float* __restrict__ s0, const float* __restrict__ s1,
    const float* __restrict__ s2, const float* __restrict__ s3,
    bf16* __restrict__ d)
{
    const int seg = blockIdx.x >> 9;
    const float* s = seg == 0 ? s0 : seg == 1 ? s1 : seg == 2 ? s2 : s3;
    const size_t off = ((size_t)(blockIdx.x & 511) * 256 + threadIdx.x) * 8;
    *(bf16x8*)&d[(size_t)seg * (E_ * E_) + off] = load8(s + off);
}

// ---------------------------------------------------------------------------
// GEMM: C[M,E] = A[M,E] @ W[E,E]^T (+ optional fp32 bias), fp32 accumulate,
// v_mfma_f32_16x16x32_bf16, 128x128 tile, BK=32, 4 waves.
// Batched over blockIdx.z (3 projections in one launch for occupancy).
// W is pre-converted bf16 -> B staging via async global_load_lds width=16.
// A staging: async if TA==bf16, manual convert if TA==float.
// M = B_*N_ = 8192, K = Nc = E_ = 1024 hardcoded.
// ---------------------------------------------------------------------------
struct GemmB { const void* A[3]; void* C[3]; };

template <typename TA, typename TC>
__global__ __launch_bounds__(256) void gemm_bt(
    GemmB batch, const bf16* __restrict__ Wb, const float* __restrict__ bias)
{
    __shared__ bf16 As[128 * 32];   // 8 KB, lane-contiguous staging layout
    __shared__ bf16 Bs[128 * 32];

    const TA*  __restrict__ A = (const TA*)batch.A[blockIdx.z];
    TC*        __restrict__ C = (TC*)batch.C[blockIdx.z];
    const bf16* __restrict__ W = Wb + (size_t)blockIdx.z * (E_ * E_);

    const int tid  = threadIdx.x;
    const int lane = tid & 63;
    const int wave = tid >> 6;
    const int wr   = wave >> 1;
    const int wc   = wave & 1;
    const int r    = lane & 15;
    const int quad = lane >> 4;

    const int m0 = blockIdx.y * 128;
    const int n0 = blockIdx.x * 128;

    // staging addressing (2 chunks of 8 elems per thread per tile)
    const int row0 = tid >> 2,          cc0 = (tid & 3) * 8;
    const int row1 = (tid + 256) >> 2,  cc1 = cc0;

    f32x4 acc[4][4];
#pragma unroll
    for (int i = 0; i < 4; i++)
#pragma unroll
        for (int j = 0; j < 4; j++)
            acc[i][j] = {0.0f, 0.0f, 0.0f, 0.0f};

    for (int k0 = 0; k0 < E_; k0 += 32) {
        __syncthreads();
        if constexpr (__is_same(TA, bf16)) {
            async_stage16(&A[(size_t)(m0 + row0) * E_ + k0 + cc0], &As[tid * 8]);
            async_stage16(&A[(size_t)(m0 + row1) * E_ + k0 + cc1], &As[(tid + 256) * 8]);
        } else {
            manual_stage16(&A[(size_t)(m0 + row0) * E_ + k0 + cc0], &As[tid * 8]);
            manual_stage16(&A[(size_t)(m0 + row1) * E_ + k0 + cc1], &As[(tid + 256) * 8]);
        }
        async_stage16(&W[(size_t)(n0 + row0) * E_ + k0 + cc0], &Bs[tid * 8]);
        async_stage16(&W[(size_t)(n0 + row1) * E_ + k0 + cc1], &Bs[(tid + 256) * 8]);
        __syncthreads();

        bf16x8 a[4], b[4];
#pragma unroll
        for (int mt = 0; mt < 4; mt++)
            a[mt] = *(const bf16x8*)&As[(wr * 64 + mt * 16 + r) * 32 + quad * 8];
#pragma unroll
        for (int nt = 0; nt < 4; nt++)
            b[nt] = *(const bf16x8*)&Bs[(wc * 64 + nt * 16 + r) * 32 + quad * 8];
#pragma unroll
        for (int mt = 0; mt < 4; mt++)
#pragma unroll
            for (int nt = 0; nt < 4; nt++)
                acc[mt][nt] = __builtin_amdgcn_mfma_f32_16x16x32_bf16(
                    a[mt], b[nt], acc[mt][nt], 0, 0, 0);
    }

    // Epilogue: C/D layout col=lane&15, row=quad*4+reg
#pragma unroll
    for (int mt = 0; mt < 4; mt++) {
#pragma unroll
        for (int nt = 0; nt < 4; nt++) {
            const int col = n0 + wc * 64 + nt * 16 + r;
            float bv = bias ? bias[col] : 0.0f;
#pragma unroll
            for (int rg = 0; rg < 4; rg++) {
                const int row = m0 + wr * 64 + mt * 16 + quad * 4 + rg;
                store_elem(C, (size_t)row * E_ + col, acc[mt][nt][rg] + bv);
            }
        }
    }
}

// ---------------------------------------------------------------------------
// MFMA flash attention. Block = 64 q-rows of one (b,h); 4 waves; wave w owns
// q-rows [w*16, w*16+16). Round-4 changes vs round-3 (which was latency-bound
// at MfmaUtil 4.7%, occupancy 10.9%):
//   (a) register prefetch of next K/V tile issued right after the compute
//       barrier -> global latency overlaps MFMA+softmax instead of sitting
//       on the critical path.
//   (b) LPT scheduling: blockIdx.x reversed so 32-tile blocks dispatch first.
// LDS row stride 72 elems (36 dwords ≡ 4 mod 32 -> worst 2-way = free, m136).
// ---------------------------------------------------------------------------
__global__ __launch_bounds__(256) void attn_fwd(
    const bf16* __restrict__ q, const bf16* __restrict__ k,
    const bf16* __restrict__ v, bf16* __restrict__ o)
{
    constexpr int LS = 72;
    __shared__ bf16 Ks[64 * LS];   // [key][d]
    __shared__ bf16 Vt[64 * LS];   // [d][key]  (transposed)
    __shared__ bf16 Ps[64 * LS];   // [q][key]  (wave-private row strips)

    const int tid  = threadIdx.x;
    const int lane = tid & 63;
    const int wave = tid >> 6;
    const int r    = lane & 15;
    const int quad = lane >> 4;

    const int bh = blockIdx.y;
    const int b  = bh >> 4;
    const int h  = bh & 15;
    const int xb = gridDim.x - 1 - blockIdx.x;   // LPT: longest blocks first
    const int q0 = xb * 64;

    const size_t basek = (size_t)b * N_ * E_ + (size_t)h * D_;

    // Q fragments (held for whole kernel): lane = Q[q=wave*16+r][d=ks*32+quad*8+j]
    bf16x8 qf[2];
    {
        const size_t qrow = ((size_t)b * N_ + q0 + wave * 16 + r) * E_ + h * D_;
        qf[0] = *(const bf16x8*)&q[qrow + quad * 8];
        qf[1] = *(const bf16x8*)&q[qrow + quad * 8 + 32];
    }

    float m_i[4], l_i[4];
    f32x4 o_acc[4];
#pragma unroll
    for (int rg = 0; rg < 4; rg++) {
        m_i[rg] = -1e30f; l_i[rg] = 0.0f;
        o_acc[rg] = {0.0f, 0.0f, 0.0f, 0.0f};
    }

    const int ntiles = xb + 1;     // causal: key tiles 0..xb

    // prefetch addressing
    const int key0 = tid >> 3;
    const int key1 = (tid + 256) >> 3;
    const int ck   = (tid & 7) * 8;
    const int kp   = tid & 31;
    const int cv   = (tid >> 5) * 8;

    bf16x8 kpre0, kpre1, vp0, vp1;
    {
        kpre0 = *(const bf16x8*)&k[basek + (size_t)key0 * E_ + ck];
        kpre1 = *(const bf16x8*)&k[basek + (size_t)key1 * E_ + ck];
        vp0   = *(const bf16x8*)&v[basek + (size_t)(2 * kp) * E_ + cv];
        vp1   = *(const bf16x8*)&v[basek + (size_t)(2 * kp + 1) * E_ + cv];
    }

    for (int t = 0; t < ntiles; t++) {
        __syncthreads();               // prev tile's reads of Ks/Vt done
        // ---- commit prefetched tile to LDS ----
        *(bf16x8*)&Ks[key0 * LS + ck] = kpre0;
        *(bf16x8*)&Ks[key1 * LS + ck] = kpre1;
#pragma unroll
        for (int e = 0; e < 8; e++) {
            union { __bf16 hh[2]; uint32_t u; } pk;
            pk.hh[0] = vp0[e]; pk.hh[1] = vp1[e];
            *(uint32_t*)&Vt[(cv + e) * LS + 2 * kp] = pk.u;
        }
        __syncthreads();

        // ---- issue prefetch for next tile (overlaps with compute) ----
        if (t + 1 < ntiles) {
            const size_t j1 = (size_t)(t + 1) * 64;
            kpre0 = *(const bf16x8*)&k[basek + (j1 + key0) * E_ + ck];
            kpre1 = *(const bf16x8*)&k[basek + (j1 + key1) * E_ + ck];
            vp0   = *(const bf16x8*)&v[basek + (j1 + 2 * kp) * E_ + cv];
            vp1   = *(const bf16x8*)&v[basek + (j1 + 2 * kp + 1) * E_ + cv];
        }

        // ---- S = scale * Q K^T ----
        f32x4 s_frag[4];
#pragma unroll
        for (int nt = 0; nt < 4; nt++) s_frag[nt] = {0.0f, 0.0f, 0.0f, 0.0f};
#pragma unroll
        for (int ks = 0; ks < 2; ks++)
#pragma unroll
            for (int nt = 0; nt < 4; nt++) {
                bf16x8 bfr = *(const bf16x8*)&Ks[(nt * 16 + r) * LS + ks * 32 + quad * 8];
                s_frag[nt] = __builtin_amdgcn_mfma_f32_16x16x32_bf16(
                    qf[ks], bfr, s_frag[nt], 0, 0, 0);
            }

        // scale + causal mask (only diagonal tile has masked entries)
        if (t == ntiles - 1) {
#pragma unroll
            for (int nt = 0; nt < 4; nt++) {
                const int kgl = t * 64 + nt * 16 + r;
#pragma unroll
                for (int rg = 0; rg < 4; rg++) {
                    const int qgl = q0 + wave * 16 + quad * 4 + rg;
                    s_frag[nt][rg] = (kgl <= qgl) ? s_frag[nt][rg] * 0.125f : -1e30f;
                }
            }
        } else {
#pragma unroll
            for (int nt = 0; nt < 4; nt++)
#pragma unroll
                for (int rg = 0; rg < 4; rg++)
                    s_frag[nt][rg] *= 0.125f;
        }

        // ---- online softmax, in-wave ----
        float mx[4];
#pragma unroll
        for (int rg = 0; rg < 4; rg++) {
            float m = fmaxf(fmaxf(s_frag[0][rg], s_frag[1][rg]),
                            fmaxf(s_frag[2][rg], s_frag[3][rg]));
            m = fmaxf(m, __shfl_xor(m, 1));
            m = fmaxf(m, __shfl_xor(m, 2));
            m = fmaxf(m, __shfl_xor(m, 4));
            m = fmaxf(m, __shfl_xor(m, 8));
            mx[rg] = m;
        }
        float alpha[4], ls[4];
#pragma unroll
        for (int rg = 0; rg < 4; rg++) {
            const float m_new = fmaxf(m_i[rg], mx[rg]);
            alpha[rg] = __expf(m_i[rg] - m_new);
            m_i[rg] = m_new;
            ls[rg] = 0.0f;
        }
#pragma unroll
        for (int nt = 0; nt < 4; nt++)
#pragma unroll
            for (int rg = 0; rg < 4; rg++) {
                const float p = __expf(s_frag[nt][rg] - m_i[rg]);
                ls[rg] += p;
                Ps[(wave * 16 + quad * 4 + rg) * LS + nt * 16 + r] = __float2bfloat16(p);
            }
#pragma unroll
        for (int rg = 0; rg < 4; rg++) {
            float s = ls[rg];
            s += __shfl_xor(s, 1);
            s += __shfl_xor(s, 2);
            s += __shfl_xor(s, 4);
            s += __shfl_xor(s, 8);
            l_i[rg] = l_i[rg] * alpha[rg] + s;
        }
#pragma unroll
        for (int nt = 0; nt < 4; nt++)
#pragma unroll
            for (int rg = 0; rg < 4; rg++)
                o_acc[nt][rg] *= alpha[rg];

        // ---- O += P V ----
#pragma unroll
        for (int ks = 0; ks < 2; ks++) {
            bf16x8 pa = *(const bf16x8*)&Ps[(wave * 16 + r) * LS + ks * 32 + quad * 8];
#pragma unroll
            for (int nt = 0; nt < 4; nt++) {
                bf16x8 vb = *(const bf16x8*)&Vt[(nt * 16 + r) * LS + ks * 32 + quad * 8];
                o_acc[nt] = __builtin_amdgcn_mfma_f32_16x16x32_bf16(
                    pa, vb, o_acc[nt], 0, 0, 0);
            }
        }
    }

    // ---- normalize + store ----
    float invl[4];
#pragma unroll
    for (int rg = 0; rg < 4; rg++) invl[rg] = 1.0f / l_i[rg];
    const size_t baseo =
        ((size_t)b * N_ + q0 + wave * 16 + quad * 4) * E_ + (size_t)h * D_;
#pragma unroll
    for (int rg = 0; rg < 4; rg++)
#pragma unroll
        for (int nt = 0; nt < 4; nt++)
            o[baseo + (size_t)rg * E_ + nt * 16 + r] =
                __float2bfloat16(o_acc[nt][rg] * invl[rg]);
}

// ---------------------------------------------------------------------------
// Inputs: xq, xk, xv, attn_mask, Wq, Wk, Wv, Wo, bo (all fp32; mask structural)
// ws: q | k | v | ao (bf16 B*N*E each) | Wb (bf16 4*E*E)  -> 75.5 MB
// ---------------------------------------------------------------------------
extern "C" void kernel_launch(void* const* d_in, const int* in_sizes, int n_in,
                              void* d_out, int out_size, void* d_ws, size_t ws_size,
                              hipStream_t stream) {
    const float* xq = (const float*)d_in[0];
    const float* xk = (const float*)d_in[1];
    const float* xv = (const float*)d_in[2];
    const float* Wq = (const float*)d_in[4];
    const float* Wk = (const float*)d_in[5];
    const float* Wv = (const float*)d_in[6];
    const float* Wo = (const float*)d_in[7];
    const float* bo = (const float*)d_in[8];
    float* out = (float*)d_out;

    const size_t elems = (size_t)B_ * N_ * E_;   // 8388608
    bf16* q  = (bf16*)d_ws;
    bf16* kk = q + elems;
    bf16* vv = kk + elems;
    bf16* ao = vv + elems;
    bf16* Wb = ao + elems;                        // 4 * E_*E_ bf16

    dim3 blk(256);
    cvt_w<<<dim3(2048), blk, 0, stream>>>(Wq, Wk, Wv, Wo, Wb);

    GemmB proj;
    proj.A[0] = xq; proj.A[1] = xk; proj.A[2] = xv;
    proj.C[0] = q;  proj.C[1] = kk; proj.C[2] = vv;
    gemm_bt<float, bf16><<<dim3(E_ / 128, (B_ * N_) / 128, 3), blk, 0, stream>>>(
        proj, Wb, nullptr);

    attn_fwd<<<dim3(N_ / 64, B_ * H_), blk, 0, stream>>>(q, kk, vv, ao);

    GemmB fin;
    fin.A[0] = ao; fin.A[1] = ao; fin.A[2] = ao;
    fin.C[0] = out; fin.C[1] = out; fin.C[2] = out;
    gemm_bt<bf16, float><<<dim3(E_ / 128, (B_ * N_) / 128, 1), blk, 0, stream>>>(
        fin, Wb + 3 * (size_t)(E_ * E_), bo);
}

// Round 5
// 396.405 us; speedup vs baseline: 8.4554x; 1.2587x over previous
//
#include <hip/hip_runtime.h>
#include <hip/hip_bf16.h>
#include <stdint.h>
#include <stddef.h>

// Problem constants (fixed by the reference)
#define B_ 4
#define N_ 2048
#define E_ 1024
#define H_ 16
#define D_ 64
// SCALE = 1/sqrt(64) = 0.125 exactly
// All reference tensors are float32; internally bf16 for MFMA.

using bf16 = __hip_bfloat16;
typedef __bf16 bf16x8 __attribute__((ext_vector_type(8)));   // 4 VGPRs, MFMA A/B frag
typedef float  f32x4  __attribute__((ext_vector_type(4)));   // MFMA C/D frag

// ---- dtype helpers --------------------------------------------------------
__device__ inline bf16x8 load8(const float* p) {
    f32x4 a = *(const f32x4*)p;
    f32x4 b = *(const f32x4*)(p + 4);
    bf16x8 r;
#pragma unroll
    for (int e = 0; e < 4; e++) { r[e] = (__bf16)a[e]; r[e + 4] = (__bf16)b[e]; }
    return r;
}
__device__ inline void store_elem(float* C, size_t idx, float v) { C[idx] = v; }
__device__ inline void store_elem(bf16* C, size_t idx, float v) {
    C[idx] = __float2bfloat16(v);
}

// Async global->LDS, 16 B per lane (LDS dest = wave-uniform base + lane*16).
__device__ inline void async_stage16(const bf16* g, bf16* l) {
    __builtin_amdgcn_global_load_lds(
        (const __attribute__((address_space(1))) uint32_t*)g,
        (__attribute__((address_space(3))) uint32_t*)l, 16, 0, 0);
}
__device__ inline void manual_stage16(const float* g, bf16* l) {
    *(bf16x8*)l = load8(g);
}

// ---------------------------------------------------------------------------
// fp32 -> bf16 convert. Blocks 0..2047: weights (512 each); blocks
// 2048..14335: the 3 inputs (4096 each). Launch grid = 2048 (weights only,
// small-ws fallback) or 14336.
// ---------------------------------------------------------------------------
__global__ __launch_bounds__(256) void cvt_all(
    const float* __restrict__ w0, const float* __restrict__ w1,
    const float* __restrict__ w2, const float* __restrict__ w3,
    bf16* __restrict__ wd,
    const float* __restrict__ x0, const float* __restrict__ x1,
    const float* __restrict__ x2,
    bf16* __restrict__ xd0, bf16* __restrict__ xd1, bf16* __restrict__ xd2)
{
    int bx = blockIdx.x;
    const float* s; bf16* d;
    if (bx < 2048) {
        const int seg = bx >> 9;
        s = seg == 0 ? w0 : seg == 1 ? w1 : seg == 2 ? w2 : w3;
        d = wd + (size_t)seg * (E_ * E_);
        bx &= 511;
    } else {
        bx -= 2048;
        const int seg = bx >> 12;
        s = seg == 0 ? x0 : seg == 1 ? x1 : x2;
        d = seg == 0 ? xd0 : seg == 1 ? xd1 : xd2;
        bx &= 4095;
    }
    const size_t off = ((size_t)bx * 256 + threadIdx.x) * 8;
    *(bf16x8*)&d[off] = load8(s + off);
}

// ---------------------------------------------------------------------------
// GEMM: C[M,E] = A[M,E] @ W[E,E]^T (+ optional fp32 bias), fp32 accumulate,
// v_mfma_f32_16x16x32_bf16, 128x128 tile, BK=32, 4 waves; batched blockIdx.z.
// bf16 A path: both operands via async global_load_lds width=16 (m97).
// ---------------------------------------------------------------------------
struct GemmB { const void* A[3]; void* C[3]; };

template <typename TA, typename TC>
__global__ __launch_bounds__(256) void gemm_bt(
    GemmB batch, const bf16* __restrict__ Wb, const float* __restrict__ bias)
{
    __shared__ bf16 As[128 * 32];
    __shared__ bf16 Bs[128 * 32];

    const TA*   __restrict__ A = (const TA*)batch.A[blockIdx.z];
    TC*         __restrict__ C = (TC*)batch.C[blockIdx.z];
    const bf16* __restrict__ W = Wb + (size_t)blockIdx.z * (E_ * E_);

    const int tid  = threadIdx.x;
    const int lane = tid & 63;
    const int wave = tid >> 6;
    const int wr   = wave >> 1;
    const int wc   = wave & 1;
    const int r    = lane & 15;
    const int quad = lane >> 4;

    const int m0 = blockIdx.y * 128;
    const int n0 = blockIdx.x * 128;

    const int row0 = tid >> 2,         cc0 = (tid & 3) * 8;
    const int row1 = (tid + 256) >> 2, cc1 = cc0;

    f32x4 acc[4][4];
#pragma unroll
    for (int i = 0; i < 4; i++)
#pragma unroll
        for (int j = 0; j < 4; j++)
            acc[i][j] = {0.0f, 0.0f, 0.0f, 0.0f};

    for (int k0 = 0; k0 < E_; k0 += 32) {
        __syncthreads();
        if constexpr (__is_same(TA, bf16)) {
            async_stage16(&A[(size_t)(m0 + row0) * E_ + k0 + cc0], &As[tid * 8]);
            async_stage16(&A[(size_t)(m0 + row1) * E_ + k0 + cc1], &As[(tid + 256) * 8]);
        } else {
            manual_stage16(&A[(size_t)(m0 + row0) * E_ + k0 + cc0], &As[tid * 8]);
            manual_stage16(&A[(size_t)(m0 + row1) * E_ + k0 + cc1], &As[(tid + 256) * 8]);
        }
        async_stage16(&W[(size_t)(n0 + row0) * E_ + k0 + cc0], &Bs[tid * 8]);
        async_stage16(&W[(size_t)(n0 + row1) * E_ + k0 + cc1], &Bs[(tid + 256) * 8]);
        __syncthreads();

        bf16x8 a[4], b[4];
#pragma unroll
        for (int mt = 0; mt < 4; mt++)
            a[mt] = *(const bf16x8*)&As[(wr * 64 + mt * 16 + r) * 32 + quad * 8];
#pragma unroll
        for (int nt = 0; nt < 4; nt++)
            b[nt] = *(const bf16x8*)&Bs[(wc * 64 + nt * 16 + r) * 32 + quad * 8];
#pragma unroll
        for (int mt = 0; mt < 4; mt++)
#pragma unroll
            for (int nt = 0; nt < 4; nt++)
                acc[mt][nt] = __builtin_amdgcn_mfma_f32_16x16x32_bf16(
                    a[mt], b[nt], acc[mt][nt], 0, 0, 0);
    }

#pragma unroll
    for (int mt = 0; mt < 4; mt++) {
#pragma unroll
        for (int nt = 0; nt < 4; nt++) {
            const int col = n0 + wc * 64 + nt * 16 + r;
            float bv = bias ? bias[col] : 0.0f;
#pragma unroll
            for (int rg = 0; rg < 4; rg++) {
                const int row = m0 + wr * 64 + mt * 16 + quad * 4 + rg;
                store_elem(C, (size_t)row * E_ + col, acc[mt][nt][rg] + bv);
            }
        }
    }
}

// ---------------------------------------------------------------------------
// MFMA flash attention, round-5: BQ=128, S^T formulation.
//
// Block = 128 q-rows of one (b,h); 4 waves; wave owns 32 q-rows as 2 strips
// (s=0,1) of 16. Computes S^T = K·Q^T (A = K from LDS, B = Q in regs) so a
// softmax row (fixed qrow = lane&15) lives in ONE lane: 16 in-register values
// x 4 quad-lanes -> reduction = 15 fmax + shfl_xor(16,32). m/l are scalars.
// P commits as 4x ds_write_b64 (was 16x b16). PV: O^T = V^T·P^T with
// A = Vt[d][key] (LDS, b128), B = Ps[qrow][key] (LDS, b128, wave-private
// rows -> no barrier). Output stored from O^T C-layout as packed 8-B stores.
//
// Why BQ=128: round-4 was latency-bound (MfmaUtil 6%, eff. ~1.2 blocks/CU);
// doubling compute per staged K/V tile makes the prefetch->consume window
// (~2x MFMA+softmax) cover L3/HBM latency within ONE block, without relying
// on co-residency. Also halves barriers and K/V traffic.
// LDS strides 72 elems (36 dwords); total 36.9 KB -> 4 blocks/CU.
// ---------------------------------------------------------------------------
__global__ __launch_bounds__(256) void attn_fwd(
    const bf16* __restrict__ q, const bf16* __restrict__ k,
    const bf16* __restrict__ v, bf16* __restrict__ o)
{
    constexpr int LS = 72;
    __shared__ bf16 Ks[64 * LS];    // [key][d]
    __shared__ bf16 Vt[64 * LS];    // [d][key]
    __shared__ bf16 Ps[128 * LS];   // [qrow][key], wave-private rows

    const int tid  = threadIdx.x;
    const int lane = tid & 63;
    const int wave = tid >> 6;
    const int r    = lane & 15;
    const int quad = lane >> 4;

    const int bh = blockIdx.y;
    const int b  = bh >> 4;
    const int h  = bh & 15;
    const int xb = gridDim.x - 1 - blockIdx.x;   // LPT: longest blocks first
    const int q0 = xb * 128;

    const size_t basek = (size_t)b * N_ * E_ + (size_t)h * D_;

    // Q as B-operand: qB[s][ks] = Q[q0+wave*32+s*16+r][ks*32+quad*8 ..+8]
    bf16x8 qB[2][2];
#pragma unroll
    for (int s = 0; s < 2; s++) {
        const size_t qrow =
            ((size_t)b * N_ + q0 + wave * 32 + s * 16 + r) * E_ + h * D_;
        qB[s][0] = *(const bf16x8*)&q[qrow + quad * 8];
        qB[s][1] = *(const bf16x8*)&q[qrow + quad * 8 + 32];
    }

    float m_i[2] = {-1e30f, -1e30f};
    float l_i[2] = {0.0f, 0.0f};
    f32x4 o_acc[4][2];              // [dt][s], O^T C-layout (row=d, col=qrow)
#pragma unroll
    for (int dt = 0; dt < 4; dt++)
#pragma unroll
        for (int s = 0; s < 2; s++)
            o_acc[dt][s] = {0.0f, 0.0f, 0.0f, 0.0f};

    const int ntiles = 2 * xb + 2;  // causal: keys 0 .. q0+127

    // prefetch addressing
    const int key0 = tid >> 3;      // 0..31
    const int key1 = key0 + 32;
    const int ck   = (tid & 7) * 8;
    const int kp   = tid & 31;
    const int cv   = (tid >> 5) * 8;

    bf16x8 kpre0 = *(const bf16x8*)&k[basek + (size_t)key0 * E_ + ck];
    bf16x8 kpre1 = *(const bf16x8*)&k[basek + (size_t)key1 * E_ + ck];
    bf16x8 vp0   = *(const bf16x8*)&v[basek + (size_t)(2 * kp) * E_ + cv];
    bf16x8 vp1   = *(const bf16x8*)&v[basek + (size_t)(2 * kp + 1) * E_ + cv];

    for (int t = 0; t < ntiles; t++) {
        __syncthreads();            // prev tile's reads of Ks/Vt done
        *(bf16x8*)&Ks[key0 * LS + ck] = kpre0;
        *(bf16x8*)&Ks[key1 * LS + ck] = kpre1;
#pragma unroll
        for (int e = 0; e < 8; e++) {
            union { __bf16 hh[2]; uint32_t u; } pk;
            pk.hh[0] = vp0[e]; pk.hh[1] = vp1[e];
            *(uint32_t*)&Vt[(cv + e) * LS + 2 * kp] = pk.u;
        }
        __syncthreads();

        if (t + 1 < ntiles) {       // overlaps with the tile's full compute
            const size_t j1 = (size_t)(t + 1) * 64;
            kpre0 = *(const bf16x8*)&k[basek + (j1 + key0) * E_ + ck];
            kpre1 = *(const bf16x8*)&k[basek + (j1 + key1) * E_ + ck];
            vp0   = *(const bf16x8*)&v[basek + (j1 + 2 * kp) * E_ + cv];
            vp1   = *(const bf16x8*)&v[basek + (j1 + 2 * kp + 1) * E_ + cv];
        }

        // ---- S^T[key][qrow] = K·Q^T : sf[mt][s], 16 MFMA ----
        f32x4 sf[4][2];
#pragma unroll
        for (int mt = 0; mt < 4; mt++)
#pragma unroll
            for (int s = 0; s < 2; s++)
                sf[mt][s] = {0.0f, 0.0f, 0.0f, 0.0f};
#pragma unroll
        for (int ks = 0; ks < 2; ks++)
#pragma unroll
            for (int mt = 0; mt < 4; mt++) {
                bf16x8 ka = *(const bf16x8*)&Ks[(mt * 16 + r) * LS + ks * 32 + quad * 8];
#pragma unroll
                for (int s = 0; s < 2; s++)
                    sf[mt][s] = __builtin_amdgcn_mfma_f32_16x16x32_bf16(
                        ka, qB[s][ks], sf[mt][s], 0, 0, 0);
            }

        // ---- scale + causal mask (only last 2 tiles can be masked) ----
        if (t >= ntiles - 2) {
#pragma unroll
            for (int mt = 0; mt < 4; mt++)
#pragma unroll
                for (int s = 0; s < 2; s++) {
                    const int qgl = q0 + wave * 32 + s * 16 + r;
#pragma unroll
                    for (int rg = 0; rg < 4; rg++) {
                        const int kgl = t * 64 + mt * 16 + quad * 4 + rg;
                        sf[mt][s][rg] =
                            (kgl <= qgl) ? sf[mt][s][rg] * 0.125f : -1e30f;
                    }
                }
        } else {
#pragma unroll
            for (int mt = 0; mt < 4; mt++)
#pragma unroll
                for (int s = 0; s < 2; s++)
#pragma unroll
                    for (int rg = 0; rg < 4; rg++)
                        sf[mt][s][rg] *= 0.125f;
        }

        // ---- online softmax per strip (row = lane-scalar) ----
#pragma unroll
        for (int s = 0; s < 2; s++) {
            float mx = sf[0][s][0];
#pragma unroll
            for (int mt = 0; mt < 4; mt++)
#pragma unroll
                for (int rg = 0; rg < 4; rg++)
                    mx = fmaxf(mx, sf[mt][s][rg]);
            mx = fmaxf(mx, __shfl_xor(mx, 16));
            mx = fmaxf(mx, __shfl_xor(mx, 32));
            const float m_new = fmaxf(m_i[s], mx);
            const float al = __expf(m_i[s] - m_new);
            m_i[s] = m_new;

            float ls = 0.0f;
            const int prow = (wave * 32 + s * 16 + r) * LS;
#pragma unroll
            for (int mt = 0; mt < 4; mt++) {
                const float p0 = __expf(sf[mt][s][0] - m_new);
                const float p1 = __expf(sf[mt][s][1] - m_new);
                const float p2 = __expf(sf[mt][s][2] - m_new);
                const float p3 = __expf(sf[mt][s][3] - m_new);
                ls += (p0 + p1) + (p2 + p3);
                union { __bf16 hh[4]; uint2 u2; } pk;
                pk.hh[0] = (__bf16)p0; pk.hh[1] = (__bf16)p1;
                pk.hh[2] = (__bf16)p2; pk.hh[3] = (__bf16)p3;
                *(uint2*)&Ps[prow + mt * 16 + quad * 4] = pk.u2;
            }
            ls += __shfl_xor(ls, 16);
            ls += __shfl_xor(ls, 32);
            l_i[s] = l_i[s] * al + ls;
#pragma unroll
            for (int dt = 0; dt < 4; dt++)
#pragma unroll
                for (int rg = 0; rg < 4; rg++)
                    o_acc[dt][s][rg] *= al;
        }

        // ---- O^T += V^T · P^T : 16 MFMA (Ps rows wave-private, no barrier) ----
#pragma unroll
        for (int ks = 0; ks < 2; ks++) {
            bf16x8 pb[2];
#pragma unroll
            for (int s = 0; s < 2; s++)
                pb[s] = *(const bf16x8*)
                    &Ps[(wave * 32 + s * 16 + r) * LS + ks * 32 + quad * 8];
#pragma unroll
            for (int dt = 0; dt < 4; dt++) {
                bf16x8 va = *(const bf16x8*)&Vt[(dt * 16 + r) * LS + ks * 32 + quad * 8];
#pragma unroll
                for (int s = 0; s < 2; s++)
                    o_acc[dt][s] = __builtin_amdgcn_mfma_f32_16x16x32_bf16(
                        va, pb[s], o_acc[dt][s], 0, 0, 0);
            }
        }
    }

    // ---- normalize + store (O^T: row=d=quad*4+rg per dt, col=qrow=r) ----
#pragma unroll
    for (int s = 0; s < 2; s++) {
        const float invl = 1.0f / l_i[s];
        const size_t orow =
            ((size_t)b * N_ + q0 + wave * 32 + s * 16 + r) * E_ + h * D_;
#pragma unroll
        for (int dt = 0; dt < 4; dt++) {
            union { __bf16 hh[4]; uint2 u2; } pk;
#pragma unroll
            for (int rg = 0; rg < 4; rg++)
                pk.hh[rg] = (__bf16)(o_acc[dt][s][rg] * invl);
            *(uint2*)&o[orow + dt * 16 + quad * 4] = pk.u2;
        }
    }
}

// ---------------------------------------------------------------------------
// Inputs: xq, xk, xv, attn_mask, Wq, Wk, Wv, Wo, bo (all fp32; mask structural)
// ws (big): q|k|v|ao (bf16 8.4M each) | Wb (4x1M) | xb0..2 (8.4M each) =126 MB
// ws (small fallback): first 75.5 MB only; proj GEMM stages fp32 A manually.
// ---------------------------------------------------------------------------
extern "C" void kernel_launch(void* const* d_in, const int* in_sizes, int n_in,
                              void* d_out, int out_size, void* d_ws, size_t ws_size,
                              hipStream_t stream) {
    const float* xq = (const float*)d_in[0];
    const float* xk = (const float*)d_in[1];
    const float* xv = (const float*)d_in[2];
    const float* Wq = (const float*)d_in[4];
    const float* Wk = (const float*)d_in[5];
    const float* Wv = (const float*)d_in[6];
    const float* Wo = (const float*)d_in[7];
    const float* bo = (const float*)d_in[8];
    float* out = (float*)d_out;

    const size_t elems = (size_t)B_ * N_ * E_;   // 8388608
    const size_t wel   = (size_t)E_ * E_;        // 1048576
    bf16* q   = (bf16*)d_ws;
    bf16* kk  = q + elems;
    bf16* vv  = kk + elems;
    bf16* ao  = vv + elems;
    bf16* Wb  = ao + elems;
    bf16* xb0 = Wb + 4 * wel;
    bf16* xb1 = xb0 + elems;
    bf16* xb2 = xb1 + elems;

    const size_t need_big = (7 * elems + 4 * wel) * 2;
    const bool big = ws_size >= need_big;

    dim3 blk(256);
    if (big) {
        cvt_all<<<dim3(14336), blk, 0, stream>>>(
            Wq, Wk, Wv, Wo, Wb, xq, xk, xv, xb0, xb1, xb2);
    } else {
        cvt_all<<<dim3(2048), blk, 0, stream>>>(
            Wq, Wk, Wv, Wo, Wb, nullptr, nullptr, nullptr,
            nullptr, nullptr, nullptr);
    }

    GemmB proj;
    if (big) { proj.A[0] = xb0; proj.A[1] = xb1; proj.A[2] = xb2; }
    else     { proj.A[0] = xq;  proj.A[1] = xk;  proj.A[2] = xv;  }
    proj.C[0] = q; proj.C[1] = kk; proj.C[2] = vv;
    if (big)
        gemm_bt<bf16, bf16><<<dim3(E_ / 128, (B_ * N_) / 128, 3), blk, 0, stream>>>(
            proj, Wb, nullptr);
    else
        gemm_bt<float, bf16><<<dim3(E_ / 128, (B_ * N_) / 128, 3), blk, 0, stream>>>(
            proj, Wb, nullptr);

    attn_fwd<<<dim3(N_ / 128, B_ * H_), blk, 0, stream>>>(q, kk, vv, ao);

    GemmB fin;
    fin.A[0] = ao; fin.A[1] = ao; fin.A[2] = ao;
    fin.C[0] = out; fin.C[1] = out; fin.C[2] = out;
    gemm_bt<bf16, float><<<dim3(E_ / 128, (B_ * N_) / 128, 1), blk, 0, stream>>>(
        fin, Wb + 3 * wel, bo);
}

// Round 6
// 345.755 us; speedup vs baseline: 9.6940x; 1.1465x over previous
//
#include <hip/hip_runtime.h>
#include <hip/hip_bf16.h>
#include <stdint.h>
#include <stddef.h>

// Problem constants (fixed by the reference)
#define B_ 4
#define N_ 2048
#define E_ 1024
#define H_ 16
#define D_ 64
// SCALE = 1/sqrt(64) = 0.125 exactly (applied by pre-scaling Q, exact in bf16)
// All reference tensors are float32; internally bf16 for MFMA.

using bf16 = __hip_bfloat16;
typedef __bf16 bf16x8 __attribute__((ext_vector_type(8)));   // 4 VGPRs, MFMA A/B frag
typedef float  f32x4  __attribute__((ext_vector_type(4)));   // MFMA C/D frag

// ---- dtype helpers --------------------------------------------------------
__device__ inline bf16x8 load8(const float* p) {
    f32x4 a = *(const f32x4*)p;
    f32x4 b = *(const f32x4*)(p + 4);
    bf16x8 r;
#pragma unroll
    for (int e = 0; e < 4; e++) { r[e] = (__bf16)a[e]; r[e + 4] = (__bf16)b[e]; }
    return r;
}
__device__ inline void store_elem(float* C, size_t idx, float v) { C[idx] = v; }
__device__ inline void store_elem(bf16* C, size_t idx, float v) {
    C[idx] = __float2bfloat16(v);
}

// Async global->LDS, 16 B per lane (LDS dest = wave-uniform base + lane*16).
__device__ inline void async_stage16(const bf16* g, bf16* l) {
    __builtin_amdgcn_global_load_lds(
        (const __attribute__((address_space(1))) uint32_t*)g,
        (__attribute__((address_space(3))) uint32_t*)l, 16, 0, 0);
}
__device__ inline void manual_stage16(const float* g, bf16* l) {
    *(bf16x8*)l = load8(g);
}

// ---------------------------------------------------------------------------
// fp32 -> bf16 convert. Blocks 0..2047: weights (512 each); blocks
// 2048..14335: the 3 inputs (4096 each).
// ---------------------------------------------------------------------------
__global__ __launch_bounds__(256) void cvt_all(
    const float* __restrict__ w0, const float* __restrict__ w1,
    const float* __restrict__ w2, const float* __restrict__ w3,
    bf16* __restrict__ wd,
    const float* __restrict__ x0, const float* __restrict__ x1,
    const float* __restrict__ x2,
    bf16* __restrict__ xd0, bf16* __restrict__ xd1, bf16* __restrict__ xd2)
{
    int bx = blockIdx.x;
    const float* s; bf16* d;
    if (bx < 2048) {
        const int seg = bx >> 9;
        s = seg == 0 ? w0 : seg == 1 ? w1 : seg == 2 ? w2 : w3;
        d = wd + (size_t)seg * (E_ * E_);
        bx &= 511;
    } else {
        bx -= 2048;
        const int seg = bx >> 12;
        s = seg == 0 ? x0 : seg == 1 ? x1 : x2;
        d = seg == 0 ? xd0 : seg == 1 ? xd1 : xd2;
        bx &= 4095;
    }
    const size_t off = ((size_t)bx * 256 + threadIdx.x) * 8;
    *(bf16x8*)&d[off] = load8(s + off);
}

// ---------------------------------------------------------------------------
// GEMM: C[M,E] = A[M,E] @ W[E,E]^T (+ optional fp32 bias), fp32 accumulate,
// v_mfma_f32_16x16x32_bf16, 128x128 tile, BK=32, 4 waves; batched blockIdx.z.
// bf16 path: both operands via async global_load_lds width=16 (m97).
// ---------------------------------------------------------------------------
struct GemmB { const void* A[3]; void* C[3]; };

template <typename TA, typename TC>
__global__ __launch_bounds__(256) void gemm_bt(
    GemmB batch, const bf16* __restrict__ Wb, const float* __restrict__ bias)
{
    __shared__ bf16 As[128 * 32];
    __shared__ bf16 Bs[128 * 32];

    const TA*   __restrict__ A = (const TA*)batch.A[blockIdx.z];
    TC*         __restrict__ C = (TC*)batch.C[blockIdx.z];
    const bf16* __restrict__ W = Wb + (size_t)blockIdx.z * (E_ * E_);

    const int tid  = threadIdx.x;
    const int lane = tid & 63;
    const int wave = tid >> 6;
    const int wr   = wave >> 1;
    const int wc   = wave & 1;
    const int r    = lane & 15;
    const int quad = lane >> 4;

    const int m0 = blockIdx.y * 128;
    const int n0 = blockIdx.x * 128;

    const int row0 = tid >> 2,         cc0 = (tid & 3) * 8;
    const int row1 = (tid + 256) >> 2, cc1 = cc0;

    f32x4 acc[4][4];
#pragma unroll
    for (int i = 0; i < 4; i++)
#pragma unroll
        for (int j = 0; j < 4; j++)
            acc[i][j] = {0.0f, 0.0f, 0.0f, 0.0f};

    for (int k0 = 0; k0 < E_; k0 += 32) {
        __syncthreads();
        if constexpr (__is_same(TA, bf16)) {
            async_stage16(&A[(size_t)(m0 + row0) * E_ + k0 + cc0], &As[tid * 8]);
            async_stage16(&A[(size_t)(m0 + row1) * E_ + k0 + cc1], &As[(tid + 256) * 8]);
        } else {
            manual_stage16(&A[(size_t)(m0 + row0) * E_ + k0 + cc0], &As[tid * 8]);
            manual_stage16(&A[(size_t)(m0 + row1) * E_ + k0 + cc1], &As[(tid + 256) * 8]);
        }
        async_stage16(&W[(size_t)(n0 + row0) * E_ + k0 + cc0], &Bs[tid * 8]);
        async_stage16(&W[(size_t)(n0 + row1) * E_ + k0 + cc1], &Bs[(tid + 256) * 8]);
        __syncthreads();

        bf16x8 a[4], b[4];
#pragma unroll
        for (int mt = 0; mt < 4; mt++)
            a[mt] = *(const bf16x8*)&As[(wr * 64 + mt * 16 + r) * 32 + quad * 8];
#pragma unroll
        for (int nt = 0; nt < 4; nt++)
            b[nt] = *(const bf16x8*)&Bs[(wc * 64 + nt * 16 + r) * 32 + quad * 8];
#pragma unroll
        for (int mt = 0; mt < 4; mt++)
#pragma unroll
            for (int nt = 0; nt < 4; nt++)
                acc[mt][nt] = __builtin_amdgcn_mfma_f32_16x16x32_bf16(
                    a[mt], b[nt], acc[mt][nt], 0, 0, 0);
    }

#pragma unroll
    for (int mt = 0; mt < 4; mt++) {
#pragma unroll
        for (int nt = 0; nt < 4; nt++) {
            const int col = n0 + wc * 64 + nt * 16 + r;
            float bv = bias ? bias[col] : 0.0f;
#pragma unroll
            for (int rg = 0; rg < 4; rg++) {
                const int row = m0 + wr * 64 + mt * 16 + quad * 4 + rg;
                store_elem(C, (size_t)row * E_ + col, acc[mt][nt][rg] + bv);
            }
        }
    }
}

// ---------------------------------------------------------------------------
// MFMA flash attention, round-6.
//
// Round-5 was idle-CU bound: grid 16x64 = exactly 4 blocks/CU and HW
// round-robin gave each CU 4 blocks of the SAME xb (tile count 2..32) ->
// 16x per-CU load imbalance, OccupancyPercent 11%.
//
// Fix: every block now processes TWO complementary q-strips (xb = 15-p then
// xb = p), so every block runs exactly 34 key-tiles -> uniform load under any
// dispatch mapping. Grid 8x64 = 512 blocks, 2/CU.
// Also: double-buffered K/V LDS -> ONE barrier per tile; commit of tile t+1
// (regs loaded a full tile earlier) overlaps compute of tile t. Q pre-scaled
// by 0.125 (exact in bf16) once per phase.
//
// S^T formulation as round-5: S^T = K·Q^T (softmax row in one lane),
// PV as O^T = V^T·P^T. LDS strides 72 elems; total 55.3 KB -> 2 blocks/CU.
// ---------------------------------------------------------------------------
__global__ __launch_bounds__(256) void attn_fwd(
    const bf16* __restrict__ q, const bf16* __restrict__ k,
    const bf16* __restrict__ v, bf16* __restrict__ o)
{
    constexpr int LS = 72;
    __shared__ bf16 Ks[2][64 * LS];   // [buf][key][d]
    __shared__ bf16 Vt[2][64 * LS];   // [buf][d][key]
    __shared__ bf16 Ps[128 * LS];     // [qrow][key], wave-private rows

    const int tid  = threadIdx.x;
    const int lane = tid & 63;
    const int wave = tid >> 6;
    const int r    = lane & 15;
    const int quad = lane >> 4;

    const int bh = blockIdx.y;
    const int b  = bh >> 4;
    const int h  = bh & 15;
    const int p  = blockIdx.x;        // 0..7

    const size_t basek = (size_t)b * N_ * E_ + (size_t)h * D_;

    // staging addressing
    const int key0 = tid >> 3;        // 0..31
    const int key1 = key0 + 32;
    const int ck   = (tid & 7) * 8;
    const int kp   = tid & 31;
    const int cv   = (tid >> 5) * 8;

#pragma unroll
    for (int ph = 0; ph < 2; ph++) {
        const int xb = ph == 0 ? (15 - p) : p;
        const int q0 = xb * 128;
        const int nt = 2 * xb + 2;    // key tiles 0..nt-1 (keys 0..q0+127)

        // Q as B-operand, pre-scaled by 0.125 (exact):
        // qB[s][ks] = 0.125*Q[q0+wave*32+s*16+r][ks*32+quad*8 ..+8]
        bf16x8 qB[2][2];
#pragma unroll
        for (int s = 0; s < 2; s++) {
            const size_t qrow =
                ((size_t)b * N_ + q0 + wave * 32 + s * 16 + r) * E_ + h * D_;
            qB[s][0] = *(const bf16x8*)&q[qrow + quad * 8];
            qB[s][1] = *(const bf16x8*)&q[qrow + quad * 8 + 32];
#pragma unroll
            for (int ks = 0; ks < 2; ks++)
#pragma unroll
                for (int e = 0; e < 8; e++)
                    qB[s][ks][e] = (__bf16)((float)qB[s][ks][e] * 0.125f);
        }

        float m_i[2] = {-1e30f, -1e30f};
        float l_i[2] = {0.0f, 0.0f};
        f32x4 o_acc[4][2];            // [dt][s], O^T C-layout
#pragma unroll
        for (int dt = 0; dt < 4; dt++)
#pragma unroll
            for (int s = 0; s < 2; s++)
                o_acc[dt][s] = {0.0f, 0.0f, 0.0f, 0.0f};

        // ---- prologue: tile 0 -> buf0; issue loads for tile 1 ----
        bf16x8 kp0, kp1, vp0, vp1;
        kp0 = *(const bf16x8*)&k[basek + (size_t)key0 * E_ + ck];
        kp1 = *(const bf16x8*)&k[basek + (size_t)key1 * E_ + ck];
        vp0 = *(const bf16x8*)&v[basek + (size_t)(2 * kp) * E_ + cv];
        vp1 = *(const bf16x8*)&v[basek + (size_t)(2 * kp + 1) * E_ + cv];
        // (prior phase ended with a barrier -> buffers free)
        *(bf16x8*)&Ks[0][key0 * LS + ck] = kp0;
        *(bf16x8*)&Ks[0][key1 * LS + ck] = kp1;
#pragma unroll
        for (int e = 0; e < 8; e++) {
            union { __bf16 hh[2]; uint32_t u; } pk;
            pk.hh[0] = vp0[e]; pk.hh[1] = vp1[e];
            *(uint32_t*)&Vt[0][(cv + e) * LS + 2 * kp] = pk.u;
        }
        {
            const size_t j1 = 64;     // tile 1 (nt >= 2 always)
            kp0 = *(const bf16x8*)&k[basek + (j1 + key0) * E_ + ck];
            kp1 = *(const bf16x8*)&k[basek + (j1 + key1) * E_ + ck];
            vp0 = *(const bf16x8*)&v[basek + (j1 + 2 * kp) * E_ + cv];
            vp1 = *(const bf16x8*)&v[basek + (j1 + 2 * kp + 1) * E_ + cv];
        }
        __syncthreads();              // buf0 visible to all waves

        for (int t = 0; t < nt; t++) {
            const int cur = t & 1;

            // ---- commit tile t+1 (regs loaded one tile ago) to other buf ----
            if (t + 1 < nt) {
                *(bf16x8*)&Ks[cur ^ 1][key0 * LS + ck] = kp0;
                *(bf16x8*)&Ks[cur ^ 1][key1 * LS + ck] = kp1;
#pragma unroll
                for (int e = 0; e < 8; e++) {
                    union { __bf16 hh[2]; uint32_t u; } pk;
                    pk.hh[0] = vp0[e]; pk.hh[1] = vp1[e];
                    *(uint32_t*)&Vt[cur ^ 1][(cv + e) * LS + 2 * kp] = pk.u;
                }
            }
            // ---- issue loads for tile t+2 (AFTER commit, so commit's vmcnt
            //      wait doesn't include them) ----
            if (t + 2 < nt) {
                const size_t j2 = (size_t)(t + 2) * 64;
                kp0 = *(const bf16x8*)&k[basek + (j2 + key0) * E_ + ck];
                kp1 = *(const bf16x8*)&k[basek + (j2 + key1) * E_ + ck];
                vp0 = *(const bf16x8*)&v[basek + (j2 + 2 * kp) * E_ + cv];
                vp1 = *(const bf16x8*)&v[basek + (j2 + 2 * kp + 1) * E_ + cv];
            }

            // ---- S^T[key][qrow] = K·(scaled Q)^T : 16 MFMA ----
            f32x4 sf[4][2];
#pragma unroll
            for (int mt = 0; mt < 4; mt++)
#pragma unroll
                for (int s = 0; s < 2; s++)
                    sf[mt][s] = {0.0f, 0.0f, 0.0f, 0.0f};
#pragma unroll
            for (int ks = 0; ks < 2; ks++)
#pragma unroll
                for (int mt = 0; mt < 4; mt++) {
                    bf16x8 ka = *(const bf16x8*)
                        &Ks[cur][(mt * 16 + r) * LS + ks * 32 + quad * 8];
#pragma unroll
                    for (int s = 0; s < 2; s++)
                        sf[mt][s] = __builtin_amdgcn_mfma_f32_16x16x32_bf16(
                            ka, qB[s][ks], sf[mt][s], 0, 0, 0);
                }

            // ---- causal mask (only last 2 tiles of the phase) ----
            if (t >= nt - 2) {
#pragma unroll
                for (int mt = 0; mt < 4; mt++)
#pragma unroll
                    for (int s = 0; s < 2; s++) {
                        const int qgl = q0 + wave * 32 + s * 16 + r;
#pragma unroll
                        for (int rg = 0; rg < 4; rg++) {
                            const int kgl = t * 64 + mt * 16 + quad * 4 + rg;
                            if (kgl > qgl) sf[mt][s][rg] = -1e30f;
                        }
                    }
            }

            // ---- online softmax per strip (row = lane-scalar) ----
#pragma unroll
            for (int s = 0; s < 2; s++) {
                float mx = sf[0][s][0];
#pragma unroll
                for (int mt = 0; mt < 4; mt++)
#pragma unroll
                    for (int rg = 0; rg < 4; rg++)
                        mx = fmaxf(mx, sf[mt][s][rg]);
                mx = fmaxf(mx, __shfl_xor(mx, 16));
                mx = fmaxf(mx, __shfl_xor(mx, 32));
                const float m_new = fmaxf(m_i[s], mx);
                const float al = __expf(m_i[s] - m_new);
                m_i[s] = m_new;

                float ls = 0.0f;
                const int prow = (wave * 32 + s * 16 + r) * LS;
#pragma unroll
                for (int mt = 0; mt < 4; mt++) {
                    const float p0 = __expf(sf[mt][s][0] - m_new);
                    const float p1 = __expf(sf[mt][s][1] - m_new);
                    const float p2 = __expf(sf[mt][s][2] - m_new);
                    const float p3 = __expf(sf[mt][s][3] - m_new);
                    ls += (p0 + p1) + (p2 + p3);
                    union { __bf16 hh[4]; uint2 u2; } pk;
                    pk.hh[0] = (__bf16)p0; pk.hh[1] = (__bf16)p1;
                    pk.hh[2] = (__bf16)p2; pk.hh[3] = (__bf16)p3;
                    *(uint2*)&Ps[prow + mt * 16 + quad * 4] = pk.u2;
                }
                ls += __shfl_xor(ls, 16);
                ls += __shfl_xor(ls, 32);
                l_i[s] = l_i[s] * al + ls;
#pragma unroll
                for (int dt = 0; dt < 4; dt++)
#pragma unroll
                    for (int rg = 0; rg < 4; rg++)
                        o_acc[dt][s][rg] *= al;
            }

            // ---- O^T += V^T · P^T (Ps rows wave-private, no barrier) ----
#pragma unroll
            for (int ks = 0; ks < 2; ks++) {
                bf16x8 pb[2];
#pragma unroll
                for (int s = 0; s < 2; s++)
                    pb[s] = *(const bf16x8*)
                        &Ps[(wave * 32 + s * 16 + r) * LS + ks * 32 + quad * 8];
#pragma unroll
                for (int dt = 0; dt < 4; dt++) {
                    bf16x8 va = *(const bf16x8*)
                        &Vt[cur][(dt * 16 + r) * LS + ks * 32 + quad * 8];
#pragma unroll
                    for (int s = 0; s < 2; s++)
                        o_acc[dt][s] = __builtin_amdgcn_mfma_f32_16x16x32_bf16(
                            va, pb[s], o_acc[dt][s], 0, 0, 0);
                }
            }

            __syncthreads();   // buf[cur] free for next commit; buf[cur^1] visible
        }

        // ---- normalize + store (O^T: row=d, col=qrow=r) ----
#pragma unroll
        for (int s = 0; s < 2; s++) {
            const float invl = 1.0f / l_i[s];
            const size_t orow =
                ((size_t)b * N_ + q0 + wave * 32 + s * 16 + r) * E_ + h * D_;
#pragma unroll
            for (int dt = 0; dt < 4; dt++) {
                union { __bf16 hh[4]; uint2 u2; } pk;
#pragma unroll
                for (int rg = 0; rg < 4; rg++)
                    pk.hh[rg] = (__bf16)(o_acc[dt][s][rg] * invl);
                *(uint2*)&o[orow + dt * 16 + quad * 4] = pk.u2;
            }
        }
    }
}

// ---------------------------------------------------------------------------
// Inputs: xq, xk, xv, attn_mask, Wq, Wk, Wv, Wo, bo (all fp32; mask structural)
// ws (big): q|k|v|ao (bf16 8.4M each) | Wb (4x1M) | xb0..2 (8.4M each) =126 MB
// ws (small fallback): first 75.5 MB only; proj GEMM stages fp32 A manually.
// ---------------------------------------------------------------------------
extern "C" void kernel_launch(void* const* d_in, const int* in_sizes, int n_in,
                              void* d_out, int out_size, void* d_ws, size_t ws_size,
                              hipStream_t stream) {
    const float* xq = (const float*)d_in[0];
    const float* xk = (const float*)d_in[1];
    const float* xv = (const float*)d_in[2];
    const float* Wq = (const float*)d_in[4];
    const float* Wk = (const float*)d_in[5];
    const float* Wv = (const float*)d_in[6];
    const float* Wo = (const float*)d_in[7];
    const float* bo = (const float*)d_in[8];
    float* out = (float*)d_out;

    const size_t elems = (size_t)B_ * N_ * E_;   // 8388608
    const size_t wel   = (size_t)E_ * E_;        // 1048576
    bf16* q   = (bf16*)d_ws;
    bf16* kk  = q + elems;
    bf16* vv  = kk + elems;
    bf16* ao  = vv + elems;
    bf16* Wb  = ao + elems;
    bf16* xb0 = Wb + 4 * wel;
    bf16* xb1 = xb0 + elems;
    bf16* xb2 = xb1 + elems;

    const size_t need_big = (7 * elems + 4 * wel) * 2;
    const bool big = ws_size >= need_big;

    dim3 blk(256);
    if (big) {
        cvt_all<<<dim3(14336), blk, 0, stream>>>(
            Wq, Wk, Wv, Wo, Wb, xq, xk, xv, xb0, xb1, xb2);
    } else {
        cvt_all<<<dim3(2048), blk, 0, stream>>>(
            Wq, Wk, Wv, Wo, Wb, nullptr, nullptr, nullptr,
            nullptr, nullptr, nullptr);
    }

    GemmB proj;
    if (big) { proj.A[0] = xb0; proj.A[1] = xb1; proj.A[2] = xb2; }
    else     { proj.A[0] = xq;  proj.A[1] = xk;  proj.A[2] = xv;  }
    proj.C[0] = q; proj.C[1] = kk; proj.C[2] = vv;
    if (big)
        gemm_bt<bf16, bf16><<<dim3(E_ / 128, (B_ * N_) / 128, 3), blk, 0, stream>>>(
            proj, Wb, nullptr);
    else
        gemm_bt<float, bf16><<<dim3(E_ / 128, (B_ * N_) / 128, 3), blk, 0, stream>>>(
            proj, Wb, nullptr);

    attn_fwd<<<dim3(8, B_ * H_), blk, 0, stream>>>(q, kk, vv, ao);

    GemmB fin;
    fin.A[0] = ao; fin.A[1] = ao; fin.A[2] = ao;
    fin.C[0] = out; fin.C[1] = out; fin.C[2] = out;
    gemm_bt<bf16, float><<<dim3(E_ / 128, (B_ * N_) / 128, 1), blk, 0, stream>>>(
        fin, Wb + 3 * wel, bo);
}